// Round 26
// baseline (104.528 us; speedup 1.0000x reference)
//
#include <hip/hip_runtime.h>
#include <hip/hip_bf16.h>

#define N_NODES 20000
#define MPAD 20032   // 313 * 64
#define CAP 64       // bucket capacity; deg ~ Poisson(16), P(deg>=64) ~ 2e-18

typedef __attribute__((ext_vector_type(8))) short short8;
typedef __attribute__((ext_vector_type(4))) float f32x4;

#define MFMA16(a,b,c) __builtin_amdgcn_mfma_f32_16x16x32_bf16(a,b,c,0,0,0)

// swizzle for [r][32-ushort] tiles (64B rows, 4 words of 16B)
#define FSW(r) (((r) & 3) ^ (((r) >> 2) & 3))

// counted-vmcnt barrier pair (T4)
#define WAIT_BAR(NSTR) do { \
  asm volatile("s_waitcnt vmcnt(" NSTR ") lgkmcnt(0)" ::: "memory"); \
  __builtin_amdgcn_s_barrier(); \
  __builtin_amdgcn_sched_barrier(0); \
} while (0)
#define END_BAR() do { \
  __builtin_amdgcn_sched_barrier(0); \
  __builtin_amdgcn_s_barrier(); \
} while (0)

static __device__ __forceinline__ ushort f2bf(float f) {
  union { float f; uint u; } v; v.f = f;
  uint u = v.u;
  uint r = (u + 0x7FFFu + ((u >> 16) & 1u)) >> 16;
  return (ushort)r;
}
static __device__ __forceinline__ float bf2f(ushort s) {
  union { uint u; float f; } v; v.u = ((uint)s) << 16; return v.f;
}

typedef __attribute__((address_space(1))) const unsigned int guint;
typedef __attribute__((address_space(3))) unsigned int luint;
static __device__ __forceinline__ void gl2lds16(const void* g, void* l) {
  __builtin_amdgcn_global_load_lds((guint*)g, (luint*)l, 16, 0, 0);
}

static __device__ __forceinline__ void cvt8(const float* __restrict__ s, ushort* __restrict__ d) {
  float4 v0 = *(const float4*)s;
  float4 v1 = *(const float4*)(s + 4);
  union { ushort u[8]; uint4 v; } t;
  t.u[0]=f2bf(v0.x); t.u[1]=f2bf(v0.y); t.u[2]=f2bf(v0.z); t.u[3]=f2bf(v0.w);
  t.u[4]=f2bf(v1.x); t.u[5]=f2bf(v1.y); t.u[6]=f2bf(v1.z); t.u[7]=f2bf(v1.w);
  *(uint4*)d = t.v;
}

// ---------------- K0: pre — XH=[x|h] bf16 (+zero pad rows) | WfcB | bucket ----------------
// roles: XH (0..2503) | WfcB (2504..2567) | bucket (2568..3817)
__global__ __launch_bounds__(256) void k_pre(
    const float* __restrict__ x, const float* __restrict__ h,
    const float* __restrict__ Wfc,
    ushort* __restrict__ XH, ushort* __restrict__ WfcB,
    const int* __restrict__ eg, int* __restrict__ cnt, int* __restrict__ srcs) {
  int bid = blockIdx.x;
  int t = threadIdx.x;

  if (bid >= 2568) {
    int e = (bid - 2568) * 256 + t;
    if (e < 320000) {
      int d = eg[320000 + e];
      int slot = atomicAdd(&cnt[d], 1);
      if (slot < CAP) srcs[d * CAP + slot] = eg[e];
    }
    return;
  }
  if (bid >= 2504) {
    int i = (bid - 2504) * 256 + t;
    cvt8(Wfc + i * 8, WfcB + i * 8);
    return;
  }
  // XH role: 2504 blocks x 512 chunks = 1,282,048 chunks (= MPAD*64)
  #pragma unroll
  for (int j = 0; j < 2; ++j) {
    int ci = bid * 512 + t + j * 256;
    int row = ci >> 6, wi = ci & 63;
    if (row < N_NODES) {
      if (wi < 32) cvt8(x + (size_t)row * 256 + wi * 8,        XH + (size_t)row * 512 + wi * 8);
      else         cvt8(h + (size_t)row * 256 + (wi - 32) * 8, XH + (size_t)row * 512 + wi * 8);
    } else {
      *(uint4*)&XH[(size_t)row * 512 + wi * 8] = make_uint4(0, 0, 0, 0);
    }
  }
}

// ---------------- K1: merged mid — fc(0..1255) | wfuse(1256..1303) | bg3hi(1304..1399) ----
__global__ __launch_bounds__(256, 4) void k_mid(
    const ushort* __restrict__ XH, const ushort* __restrict__ WfcB,
    const float* __restrict__ bfc, ushort* __restrict__ AX,
    const float* __restrict__ Wih, const float* __restrict__ Wc,
    const float* __restrict__ Whh, ushort* __restrict__ Bg3) {
  __shared__ __attribute__((aligned(16))) ushort smem[16384];  // 32 KB
  int bid = blockIdx.x;
  int t = threadIdx.x, w = t >> 6, l = t & 63;

  if (bid >= 1304) {
    // ---- bg3hi role: Bg3[row][256:512] = Whh_p rows (96 blocks x 256 chunks)
    int i = (bid - 1304) * 256 + t;
    int row = i >> 5;
    int k0 = (i & 31) * 8;
    int g = row / 48, rem = row - g * 48;
    int p = rem >> 4, ci = rem & 15;
    int c = g * 16 + ci;
    cvt8(Whh + ((size_t)(p * 256 + c)) * 256 + k0, Bg3 + (size_t)row * 512 + 256 + k0);
    return;
  }

  if (bid >= 1256) {
    // ---- wfuse role: Bg3 lo = G, G[tc][jj] = dot(Wc row tc, Wih row jj), f32-direct ----
    ushort* sA = smem;
    ushort* sB = smem + 2048;
    int wf = bid - 1256;                  // 0..47
    int row0 = (wf % 12) * 64, col0 = (wf / 12) * 64;
    int wr = (w >> 1) * 32, wc = (w & 1) * 32;
    f32x4 acc[2][2] = {};
    for (int ks = 0; ks < 8; ++ks) {
      int k0 = ks * 32;
      {
        int r = t >> 2, wl = t & 3;
        int gw = wl ^ FSW(r);
        cvt8(Wih + (size_t)(row0 + r) * 256 + k0 + gw * 8, &sA[r*32 + wl*8]);
        cvt8(Wc  + (size_t)(col0 + r) * 256 + k0 + gw * 8, &sB[r*32 + wl*8]);
      }
      __syncthreads();
      short8 af[2], bfr[2];
      #pragma unroll
      for (int mi = 0; mi < 2; ++mi) {
        int r = wr + mi * 16 + (l & 15);
        af[mi] = *(short8*)&sA[r * 32 + (((l >> 4)) ^ FSW(r)) * 8];
      }
      #pragma unroll
      for (int ni = 0; ni < 2; ++ni) {
        int br = wc + ni * 16 + (l & 15);
        bfr[ni] = *(short8*)&sB[br * 32 + (((l >> 4)) ^ FSW(br)) * 8];
      }
      #pragma unroll
      for (int mi = 0; mi < 2; ++mi)
        #pragma unroll
        for (int ni = 0; ni < 2; ++ni)
          acc[mi][ni] = MFMA16(af[mi], bfr[ni], acc[mi][ni]);
      __syncthreads();
    }
    #pragma unroll
    for (int mi = 0; mi < 2; ++mi)
      #pragma unroll
      for (int ni = 0; ni < 2; ++ni)
        #pragma unroll
        for (int q = 0; q < 4; ++q) {
          int jj = row0 + wr + mi*16 + (l>>4)*4 + q;   // Wih row (gate-major)
          int tc = col0 + wc + ni*16 + (l&15);         // k index (S dim)
          int p = jj >> 8, c = jj & 255;
          int brow = (c >> 4) * 48 + p * 16 + (c & 15);
          Bg3[(size_t)brow * 512 + tc] = f2bf(acc[mi][ni][q]);
        }
    return;
  }

  // ---- fc role: gru3-clone. xr = relu([x|h]@Wfc^T + b) -> AX[:,256:512].
  // 64r x 64c, BK=64, bf16 gl2lds staging (4 issues/wave), counted vmcnt, 2 buffers.
  ushort* A0 = smem;            // 64*64
  ushort* B0 = smem + 4096;
  ushort* A1 = smem + 8192;
  ushort* B1 = smem + 12288;
  int wk = (bid & 7) * 157 + (bid >> 3);   // XCD-bijective (1256 = 8*157)
  int panel = wk >> 2, ch = wk & 3;
  if (panel >= 313) return;
  int row0 = panel * 64, col0 = ch * 64;
  int wr = (w >> 1) * 32, wc = (w & 1) * 32;

  // stage lambda-equivalent: A from XH, B from WfcB (rows = output cols), 4 issues/wave
  #define FC_STAGE(sa, sb, KS) do { \
    int k0_ = (KS) * 64; \
    _Pragma("unroll") \
    for (int j = 0; j < 2; ++j) { \
      int rb = w * 16 + j * 8; \
      int r = rb + (l >> 3); \
      int gw = (l & 7) ^ (r & 7); \
      gl2lds16(XH + (size_t)(row0 + r) * 512 + k0_ + gw * 8, (char*)(sa) + (size_t)rb * 128); \
    } \
    _Pragma("unroll") \
    for (int j = 0; j < 2; ++j) { \
      int rb = w * 16 + j * 8; \
      int r = rb + (l >> 3); \
      int gw = (l & 7) ^ (r & 7); \
      gl2lds16(WfcB + (size_t)(col0 + r) * 512 + k0_ + gw * 8, (char*)(sb) + (size_t)rb * 128); \
    } \
  } while (0)

  FC_STAGE(A0, B0, 0);
  __syncthreads();                     // prologue: full drain, buf0 ready

  f32x4 acc[2][2] = {};
  #pragma unroll
  for (int ks = 0; ks < 8; ++ks) {
    ushort* cA = (ks & 1) ? A1 : A0;
    ushort* cB = (ks & 1) ? B1 : B0;
    ushort* nA = (ks & 1) ? A0 : A1;
    ushort* nB = (ks & 1) ? B0 : B1;
    if (ks < 7) FC_STAGE(nA, nB, ks + 1);   // 4 issues/wave stay in flight
    if (ks < 7) WAIT_BAR("4");
    else        WAIT_BAR("0");
    __builtin_amdgcn_s_setprio(1);
    #pragma unroll
    for (int j = 0; j < 2; ++j) {      // two K=32 sub-steps, 8 MFMA total
      short8 af[2], bfr[2];
      #pragma unroll
      for (int mi = 0; mi < 2; ++mi) {
        int r = wr + mi * 16 + (l & 15);
        af[mi] = *(short8*)&cA[r * 64 + ((j * 4 + (l >> 4)) ^ (r & 7)) * 8];
      }
      #pragma unroll
      for (int ni = 0; ni < 2; ++ni) {
        int br = wc + ni * 16 + (l & 15);
        bfr[ni] = *(short8*)&cB[br * 64 + ((j * 4 + (l >> 4)) ^ (br & 7)) * 8];
      }
      #pragma unroll
      for (int mi = 0; mi < 2; ++mi)
        #pragma unroll
        for (int ni = 0; ni < 2; ++ni)
          acc[mi][ni] = MFMA16(af[mi], bfr[ni], acc[mi][ni]);
    }
    __builtin_amdgcn_s_setprio(0);
    END_BAR();
  }
  #undef FC_STAGE
  #pragma unroll
  for (int mi = 0; mi < 2; ++mi)
    #pragma unroll
    for (int ni = 0; ni < 2; ++ni)
      #pragma unroll
      for (int q = 0; q < 4; ++q) {
        int r = row0 + wr + mi*16 + (l>>4)*4 + q;
        int c = col0 + wc + ni*16 + (l&15);
        if (r < N_NODES) {
          float v = acc[mi][ni][q] + bfc[c];
          v = v > 0.f ? v : 0.f;
          AX[(size_t)r * 512 + 256 + c] = f2bf(v);
        }
      }
}

// ---------------- gather-sum S[n] = sum xr[src in bucket n] -> AX[:,0:256] ----------
__global__ __launch_bounds__(256) void k_aggS(
    const int* __restrict__ cnt, const int* __restrict__ srcs,
    ushort* __restrict__ AX) {
  int node = blockIdx.x * 8 + (threadIdx.x >> 5);
  if (node >= N_NODES) return;
  int lane = threadIdx.x & 31;
  const int* bkt = srcs + node * CAP;
  int n = cnt[node]; if (n > CAP) n = CAP;
  float a[8] = {};
  int i = 0;
  for (; i + 4 <= n; i += 4) {
    uint4 v0 = *(const uint4*)(AX + (size_t)bkt[i  ] * 512 + 256 + lane * 8);
    uint4 v1 = *(const uint4*)(AX + (size_t)bkt[i+1] * 512 + 256 + lane * 8);
    uint4 v2 = *(const uint4*)(AX + (size_t)bkt[i+2] * 512 + 256 + lane * 8);
    uint4 v3 = *(const uint4*)(AX + (size_t)bkt[i+3] * 512 + 256 + lane * 8);
    const ushort* p0 = (const ushort*)&v0; const ushort* p1 = (const ushort*)&v1;
    const ushort* p2 = (const ushort*)&v2; const ushort* p3 = (const ushort*)&v3;
    #pragma unroll
    for (int j = 0; j < 8; j++) a[j] += (bf2f(p0[j]) + bf2f(p1[j])) + (bf2f(p2[j]) + bf2f(p3[j]));
  }
  for (; i < n; ++i) {
    uint4 v0 = *(const uint4*)(AX + (size_t)bkt[i] * 512 + 256 + lane * 8);
    const ushort* p0 = (const ushort*)&v0;
    #pragma unroll
    for (int j = 0; j < 8; j++) a[j] += bf2f(p0[j]);
  }
  union { ushort s[8]; uint4 v; } o;
  #pragma unroll
  for (int j = 0; j < 8; j++) o.s[j] = f2bf(a[j]);
  *(uint4*)(AX + (size_t)node * 512 + lane * 8) = o.v;
}

// ---------------- K3: fused GRU, 3-plane K=512, 2-phase + COUNTED vmcnt ----------------
static __device__ __forceinline__ void gru3_stage(
    const ushort* __restrict__ AX, const ushort* __restrict__ Bg3,
    ushort* sA, ushort* sB, int row0, int bro, int w, int l, int ks) {
  int k0 = ks * 64;
  #pragma unroll
  for (int j = 0; j < 2; ++j) {      // A: 64 rows, 2 issues/wave
    int rb = w * 16 + j * 8;
    int r = rb + (l >> 3);
    int gw = (l & 7) ^ (r & 7);
    gl2lds16(AX + (size_t)(row0 + r) * 512 + k0 + gw * 8, (char*)sA + (size_t)rb * 128);
  }
  #pragma unroll
  for (int j = 0; j < 6; ++j) {      // B: 192 rows, 6 issues/wave
    int rb = j * 32 + w * 8;
    int r = rb + (l >> 3);
    int gw = (l & 7) ^ (r & 7);
    gl2lds16(Bg3 + (size_t)(bro + r) * 512 + k0 + gw * 8, (char*)sB + (size_t)rb * 128);
  }
}   // exactly 8 gl2lds per wave

template<int PN>
static __device__ __forceinline__ void gru3_compute(
    const ushort* sA, const ushort* sB, int w, int l, f32x4 (&acc)[4][4]) {
  __builtin_amdgcn_s_setprio(1);
  #pragma unroll
  for (int j = 0; j < 2; ++j) {      // two K=32 sub-steps
    short8 af[4], bfr[3];
    #pragma unroll
    for (int mi = 0; mi < 4; ++mi) {
      int r = mi * 16 + (l & 15);
      af[mi] = *(const short8*)&sA[r * 64 + ((j * 4 + (l >> 4)) ^ (r & 7)) * 8];
    }
    #pragma unroll
    for (int p = 0; p < 3; ++p) {
      int br = w * 48 + p * 16 + (l & 15);
      bfr[p] = *(const short8*)&sB[br * 64 + ((j * 4 + (l >> 4)) ^ (br & 7)) * 8];
    }
    #pragma unroll
    for (int mi = 0; mi < 4; ++mi) {
      acc[mi][0]  = MFMA16(af[mi], bfr[0], acc[mi][0]);
      acc[mi][1]  = MFMA16(af[mi], bfr[1], acc[mi][1]);
      acc[mi][PN] = MFMA16(af[mi], bfr[2], acc[mi][PN]);
    }
  }
  __builtin_amdgcn_s_setprio(0);
}

__global__ __launch_bounds__(256, 2) void k_gru3(
    const ushort* __restrict__ AX, const ushort* __restrict__ Bg3,
    const float* __restrict__ bih, const float* __restrict__ bhh,
    float* __restrict__ out) {
  __shared__ __attribute__((aligned(16))) ushort smem[2 * 16384];  // 64 KB
  ushort* sA0 = smem;               // 64*64
  ushort* sB0 = smem + 4096;        // 192*64
  ushort* sA1 = smem + 16384;
  ushort* sB1 = smem + 20480;
  int bid = blockIdx.x;
  int wk = (bid & 7) * 157 + (bid >> 3);   // XCD-bijective (1256 = 8*157)
  int panel = wk >> 2, ch = wk & 3;
  if (panel >= 313) return;
  int row0 = panel * 64;
  int bro = ch * 192;                  // Bg3 row offset
  int t = threadIdx.x, w = t >> 6, l = t & 63;

  gru3_stage(AX, Bg3, sA0, sB0, row0, bro, w, l, 0);
  __syncthreads();                     // prologue: full drain, buf0 ready

  f32x4 acc[4][4] = {};                // [mi][r, z, i_n, h_n]
  #pragma unroll
  for (int ks = 0; ks < 8; ++ks) {
    ushort* cA = (ks & 1) ? sA1 : sA0;
    ushort* cB = (ks & 1) ? sB1 : sB0;
    ushort* nA = (ks & 1) ? sA0 : sA1;
    ushort* nB = (ks & 1) ? sB0 : sB1;
    if (ks < 7) gru3_stage(AX, Bg3, nA, nB, row0, bro, w, l, ks + 1);  // 8 issues
    if (ks < 7) WAIT_BAR("8");         // prev iter's 8 retired -> cur tile ready
    else        WAIT_BAR("0");
    if (ks < 4) gru3_compute<2>(cA, cB, w, l, acc);
    else        gru3_compute<3>(cA, cB, w, l, acc);
    END_BAR();                         // all waves done reading cur buffers
  }

  int c = ch * 64 + w * 16 + (l & 15);
  float br_ = bih[c] + bhh[c];
  float bz_ = bih[256 + c] + bhh[256 + c];
  float bi_ = bih[512 + c];
  float bh_ = bhh[512 + c];
  #pragma unroll
  for (int mi = 0; mi < 4; ++mi)
    #pragma unroll
    for (int q = 0; q < 4; ++q) {
      int r = row0 + mi*16 + (l>>4)*4 + q;
      if (r < N_NODES) {
        float rg = 1.f / (1.f + __expf(-(acc[mi][0][q] + br_)));
        float zg = 1.f / (1.f + __expf(-(acc[mi][1][q] + bz_)));
        float ng = tanhf((acc[mi][2][q] + bi_) + rg * (acc[mi][3][q] + bh_));
        float xv = bf2f(AX[(size_t)r * 512 + 256 + c]);
        out[(size_t)r * 256 + c] = (1.f - zg) * ng + zg * xv;
      }
    }
}

extern "C" void kernel_launch(void* const* d_in, const int* in_sizes, int n_in,
                              void* d_out, int out_size, void* d_ws, size_t ws_size,
                              hipStream_t stream) {
  const float* h   = (const float*)d_in[0];
  const float* x   = (const float*)d_in[1];
  const float* Wfc = (const float*)d_in[3];
  const float* bfc = (const float*)d_in[4];
  const float* Wc  = (const float*)d_in[5];
  const float* Wih = (const float*)d_in[6];
  const float* Whh = (const float*)d_in[7];
  const float* bih = (const float*)d_in[8];
  const float* bhh = (const float*)d_in[9];
  const int*   eg  = (const int*)d_in[10];
  float* out = (float*)d_out;

  char* ws = (char*)d_ws;
  ushort* AX   = (ushort*)(ws);                  // MPAD*512*2 = 20,512,768
  ushort* XH   = (ushort*)(ws + 20512768);       // 20,512,768
  ushort* Bg3  = (ushort*)(ws + 41025536);       //    786,432
  ushort* WfcB = (ushort*)(ws + 41811968);       //    262,144
  int*    cnt    = (int*)(ws + 42074112);        //     80,000
  int*    srcs   = (int*)(ws + 42154112);        //  5,120,000 -> 47,274,112 total

  hipMemsetAsync(cnt, 0, (size_t)N_NODES * 4, stream);

  // pre: XH (2504) | WfcB (64) | bucket (1250)
  k_pre<<<3818, 256, 0, stream>>>(x, h, Wfc, XH, WfcB, eg, cnt, srcs);

  // mid: fc (1256) | wfuse (48) | bg3hi (96)
  k_mid<<<1400, 256, 0, stream>>>(XH, WfcB, bfc, AX, Wih, Wc, Whh, Bg3);

  k_aggS<<<(N_NODES + 7) / 8, 256, 0, stream>>>(cnt, srcs, AX);

  k_gru3<<<1256, 256, 0, stream>>>(AX, Bg3, bih, bhh, out);
}

// Round 27
// 88.662 us; speedup vs baseline: 1.1789x; 1.1789x over previous
//
#include <hip/hip_runtime.h>
#include <hip/hip_bf16.h>

#define N_NODES 20000
#define MPAD 20032   // 313 * 64
#define CAP 64       // bucket capacity; deg ~ Poisson(16), P(deg>=64) ~ 2e-18

typedef __attribute__((ext_vector_type(8))) short short8;
typedef __attribute__((ext_vector_type(4))) float f32x4;

#define MFMA16(a,b,c) __builtin_amdgcn_mfma_f32_16x16x32_bf16(a,b,c,0,0,0)

// swizzle for [r][32-ushort] tiles (64B rows, 4 words of 16B)
#define FSW(r) (((r) & 3) ^ (((r) >> 2) & 3))

// counted-vmcnt barrier pair (T4)
#define WAIT_BAR(NSTR) do { \
  asm volatile("s_waitcnt vmcnt(" NSTR ") lgkmcnt(0)" ::: "memory"); \
  __builtin_amdgcn_s_barrier(); \
  __builtin_amdgcn_sched_barrier(0); \
} while (0)
#define END_BAR() do { \
  __builtin_amdgcn_sched_barrier(0); \
  __builtin_amdgcn_s_barrier(); \
} while (0)

static __device__ __forceinline__ ushort f2bf(float f) {
  union { float f; uint u; } v; v.f = f;
  uint u = v.u;
  uint r = (u + 0x7FFFu + ((u >> 16) & 1u)) >> 16;
  return (ushort)r;
}
static __device__ __forceinline__ float bf2f(ushort s) {
  union { uint u; float f; } v; v.u = ((uint)s) << 16; return v.f;
}

typedef __attribute__((address_space(1))) const unsigned int guint;
typedef __attribute__((address_space(3))) unsigned int luint;
static __device__ __forceinline__ void gl2lds16(const void* g, void* l) {
  __builtin_amdgcn_global_load_lds((guint*)g, (luint*)l, 16, 0, 0);
}

static __device__ __forceinline__ void cvt8(const float* __restrict__ s, ushort* __restrict__ d) {
  float4 v0 = *(const float4*)s;
  float4 v1 = *(const float4*)(s + 4);
  union { ushort u[8]; uint4 v; } t;
  t.u[0]=f2bf(v0.x); t.u[1]=f2bf(v0.y); t.u[2]=f2bf(v0.z); t.u[3]=f2bf(v0.w);
  t.u[4]=f2bf(v1.x); t.u[5]=f2bf(v1.y); t.u[6]=f2bf(v1.z); t.u[7]=f2bf(v1.w);
  *(uint4*)d = t.v;
}
// load 8 f32, cvt to bf16x8, store to LDS word slot
static __device__ __forceinline__ void cvt8_lds(const float* __restrict__ s, ushort* d) {
  float4 v0 = *(const float4*)s;
  float4 v1 = *(const float4*)(s + 4);
  union { ushort u[8]; uint4 v; } t;
  t.u[0]=f2bf(v0.x); t.u[1]=f2bf(v0.y); t.u[2]=f2bf(v0.z); t.u[3]=f2bf(v0.w);
  t.u[4]=f2bf(v1.x); t.u[5]=f2bf(v1.y); t.u[6]=f2bf(v1.z); t.u[7]=f2bf(v1.w);
  *(uint4*)d = t.v;
}

// ---------------- K1: merged mid — fc(0..1255) | wfuse(1256..1303) | bg3hi(1304..1399)
//                                 | bucket(1400..2649). No prep kernel needed.
__global__ __launch_bounds__(256, 4) void k_mid(
    const float* __restrict__ x, const float* __restrict__ h,
    const float* __restrict__ Wfc, const float* __restrict__ bfc,
    ushort* __restrict__ AX,
    const float* __restrict__ Wih, const float* __restrict__ Wc,
    const float* __restrict__ Whh, ushort* __restrict__ Bg3,
    const int* __restrict__ eg, int* __restrict__ cnt, int* __restrict__ srcs) {
  __shared__ __attribute__((aligned(16))) ushort smem[8192];  // 16 KB
  int bid = blockIdx.x;
  int t = threadIdx.x, w = t >> 6, l = t & 63;

  if (bid >= 1400) {
    // ---- bucket role: 1250 blocks cover 320000 edges exactly ----
    int e = (bid - 1400) * 256 + t;
    if (e < 320000) {
      int d = eg[320000 + e];
      int slot = atomicAdd(&cnt[d], 1);
      if (slot < CAP) srcs[d * CAP + slot] = eg[e];
    }
    return;
  }

  if (bid >= 1304) {
    // ---- bg3hi role: Bg3[row][256:512] = Whh_p rows (96 blocks x 256 = 24576 chunks)
    int i = (bid - 1304) * 256 + t;
    int row = i >> 5;
    int k0 = (i & 31) * 8;
    int g = row / 48, rem = row - g * 48;
    int p = rem >> 4, ci = rem & 15;
    int c = g * 16 + ci;
    cvt8(Whh + ((size_t)(p * 256 + c)) * 256 + k0, Bg3 + (size_t)row * 512 + 256 + k0);
    return;
  }

  if (bid >= 1256) {
    // ---- wfuse role: Bg3 lo = G, G[tc][jj] = dot(Wc row tc, Wih row jj), f32-direct ----
    ushort* sA = smem;
    ushort* sB = smem + 2048;
    int wf = bid - 1256;                  // 0..47
    int row0 = (wf % 12) * 64, col0 = (wf / 12) * 64;
    int wr = (w >> 1) * 32, wc = (w & 1) * 32;
    f32x4 acc[2][2] = {};
    for (int ks = 0; ks < 8; ++ks) {
      int k0 = ks * 32;
      {
        int r = t >> 2, wl = t & 3;
        int gw = wl ^ FSW(r);
        cvt8_lds(Wih + (size_t)(row0 + r) * 256 + k0 + gw * 8, &sA[r*32 + wl*8]);
        cvt8_lds(Wc  + (size_t)(col0 + r) * 256 + k0 + gw * 8, &sB[r*32 + wl*8]);
      }
      __syncthreads();
      short8 af[2], bfr[2];
      #pragma unroll
      for (int mi = 0; mi < 2; ++mi) {
        int r = wr + mi * 16 + (l & 15);
        af[mi] = *(short8*)&sA[r * 32 + (((l >> 4)) ^ FSW(r)) * 8];
      }
      #pragma unroll
      for (int ni = 0; ni < 2; ++ni) {
        int br = wc + ni * 16 + (l & 15);
        bfr[ni] = *(short8*)&sB[br * 32 + (((l >> 4)) ^ FSW(br)) * 8];
      }
      #pragma unroll
      for (int mi = 0; mi < 2; ++mi)
        #pragma unroll
        for (int ni = 0; ni < 2; ++ni)
          acc[mi][ni] = MFMA16(af[mi], bfr[ni], acc[mi][ni]);
      __syncthreads();
    }
    #pragma unroll
    for (int mi = 0; mi < 2; ++mi)
      #pragma unroll
      for (int ni = 0; ni < 2; ++ni)
        #pragma unroll
        for (int q = 0; q < 4; ++q) {
          int jj = row0 + wr + mi*16 + (l>>4)*4 + q;   // Wih row (gate-major)
          int tc = col0 + wc + ni*16 + (l&15);         // k index (S dim)
          int p = jj >> 8, c = jj & 255;
          int brow = (c >> 4) * 48 + p * 16 + (c & 15);
          Bg3[(size_t)brow * 512 + tc] = f2bf(acc[mi][ni][q]);
        }
    return;
  }

  // ---- fc role: xr = relu([x|h]@Wfc^T + b) -> AX[:,256:512]. 64r x 64c, BK=64 ----
  // 8 iters (half the barriers of BK=32); A and B both reg-staged from f32.
  // 1-D XCD-bijective over 1256 (=8*157); panel's 4 col-chunks share XCD L2.
  ushort* sA = smem;          // [64][64] bf16, (r&7) word swizzle
  ushort* sB = smem + 4096;
  int wk = (bid & 7) * 157 + (bid >> 3);
  int panel = wk >> 2, ch = wk & 3;
  if (panel >= 313) return;
  int row0 = panel * 64, col0 = ch * 64;
  int wr = (w >> 1) * 32, wc = (w & 1) * 32;

  f32x4 acc[2][2] = {};
  for (int ks = 0; ks < 8; ++ks) {
    int k0 = ks * 64;
    const float* Af = (ks < 4) ? x : h;
    int ka = k0 & 255;
    // A: 512 chunks (2/thread), f32 -> bf16 reg-stage; source-word swizzled
    #pragma unroll
    for (int j = 0; j < 2; ++j) {
      int ci = t + j * 256;
      int r = ci >> 3, wl = ci & 7;
      int gw = wl ^ (r & 7);
      int gr = row0 + r; if (gr > N_NODES - 1) gr = N_NODES - 1;
      cvt8_lds(Af + (size_t)gr * 256 + ka + gw * 8, &sA[r*64 + wl*8]);
    }
    // B: 512 chunks (2/thread), f32 Wfc rows (output cols), same swizzle
    #pragma unroll
    for (int j = 0; j < 2; ++j) {
      int ci = t + j * 256;
      int r = ci >> 3, wl = ci & 7;
      int gw = wl ^ (r & 7);
      cvt8_lds(Wfc + (size_t)(col0 + r) * 512 + k0 + gw * 8, &sB[r*64 + wl*8]);
    }
    __syncthreads();
    #pragma unroll
    for (int j = 0; j < 2; ++j) {      // two K=32 sub-steps
      short8 af[2], bfr[2];
      #pragma unroll
      for (int mi = 0; mi < 2; ++mi) {
        int r = wr + mi * 16 + (l & 15);
        af[mi] = *(short8*)&sA[r * 64 + ((j * 4 + (l >> 4)) ^ (r & 7)) * 8];
      }
      #pragma unroll
      for (int ni = 0; ni < 2; ++ni) {
        int br = wc + ni * 16 + (l & 15);
        bfr[ni] = *(short8*)&sB[br * 64 + ((j * 4 + (l >> 4)) ^ (br & 7)) * 8];
      }
      #pragma unroll
      for (int mi = 0; mi < 2; ++mi)
        #pragma unroll
        for (int ni = 0; ni < 2; ++ni)
          acc[mi][ni] = MFMA16(af[mi], bfr[ni], acc[mi][ni]);
    }
    __syncthreads();
  }
  #pragma unroll
  for (int mi = 0; mi < 2; ++mi)
    #pragma unroll
    for (int ni = 0; ni < 2; ++ni)
      #pragma unroll
      for (int q = 0; q < 4; ++q) {
        int r = row0 + wr + mi*16 + (l>>4)*4 + q;
        int c = col0 + wc + ni*16 + (l&15);
        if (r < N_NODES) {
          float v = acc[mi][ni][q] + bfc[c];
          v = v > 0.f ? v : 0.f;
          AX[(size_t)r * 512 + 256 + c] = f2bf(v);
        }
      }
}

// ---------------- gather-sum S[n] = sum xr[src in bucket n] -> AX[:,0:256] ----------
__global__ __launch_bounds__(256) void k_aggS(
    const int* __restrict__ cnt, const int* __restrict__ srcs,
    ushort* __restrict__ AX) {
  int node = blockIdx.x * 8 + (threadIdx.x >> 5);
  if (node >= N_NODES) return;
  int lane = threadIdx.x & 31;
  const int* bkt = srcs + node * CAP;
  int n = cnt[node]; if (n > CAP) n = CAP;
  float a[8] = {};
  int i = 0;
  for (; i + 4 <= n; i += 4) {
    uint4 v0 = *(const uint4*)(AX + (size_t)bkt[i  ] * 512 + 256 + lane * 8);
    uint4 v1 = *(const uint4*)(AX + (size_t)bkt[i+1] * 512 + 256 + lane * 8);
    uint4 v2 = *(const uint4*)(AX + (size_t)bkt[i+2] * 512 + 256 + lane * 8);
    uint4 v3 = *(const uint4*)(AX + (size_t)bkt[i+3] * 512 + 256 + lane * 8);
    const ushort* p0 = (const ushort*)&v0; const ushort* p1 = (const ushort*)&v1;
    const ushort* p2 = (const ushort*)&v2; const ushort* p3 = (const ushort*)&v3;
    #pragma unroll
    for (int j = 0; j < 8; j++) a[j] += (bf2f(p0[j]) + bf2f(p1[j])) + (bf2f(p2[j]) + bf2f(p3[j]));
  }
  for (; i < n; ++i) {
    uint4 v0 = *(const uint4*)(AX + (size_t)bkt[i] * 512 + 256 + lane * 8);
    const ushort* p0 = (const ushort*)&v0;
    #pragma unroll
    for (int j = 0; j < 8; j++) a[j] += bf2f(p0[j]);
  }
  union { ushort s[8]; uint4 v; } o;
  #pragma unroll
  for (int j = 0; j < 8; j++) o.s[j] = f2bf(a[j]);
  *(uint4*)(AX + (size_t)node * 512 + lane * 8) = o.v;
}

// ---------------- K3: fused GRU, 3-plane K=512, 2-phase + COUNTED vmcnt ----------------
static __device__ __forceinline__ void gru3_stage(
    const ushort* __restrict__ AX, const ushort* __restrict__ Bg3,
    ushort* sA, ushort* sB, int row0, int bro, int w, int l, int ks) {
  int k0 = ks * 64;
  #pragma unroll
  for (int j = 0; j < 2; ++j) {      // A: 64 rows, 2 issues/wave
    int rb = w * 16 + j * 8;
    int r = rb + (l >> 3);
    int gw = (l & 7) ^ (r & 7);
    gl2lds16(AX + (size_t)(row0 + r) * 512 + k0 + gw * 8, (char*)sA + (size_t)rb * 128);
  }
  #pragma unroll
  for (int j = 0; j < 6; ++j) {      // B: 192 rows, 6 issues/wave
    int rb = j * 32 + w * 8;
    int r = rb + (l >> 3);
    int gw = (l & 7) ^ (r & 7);
    gl2lds16(Bg3 + (size_t)(bro + r) * 512 + k0 + gw * 8, (char*)sB + (size_t)rb * 128);
  }
}   // exactly 8 gl2lds per wave

template<int PN>
static __device__ __forceinline__ void gru3_compute(
    const ushort* sA, const ushort* sB, int w, int l, f32x4 (&acc)[4][4]) {
  __builtin_amdgcn_s_setprio(1);
  #pragma unroll
  for (int j = 0; j < 2; ++j) {      // two K=32 sub-steps
    short8 af[4], bfr[3];
    #pragma unroll
    for (int mi = 0; mi < 4; ++mi) {
      int r = mi * 16 + (l & 15);
      af[mi] = *(const short8*)&sA[r * 64 + ((j * 4 + (l >> 4)) ^ (r & 7)) * 8];
    }
    #pragma unroll
    for (int p = 0; p < 3; ++p) {
      int br = w * 48 + p * 16 + (l & 15);
      bfr[p] = *(const short8*)&sB[br * 64 + ((j * 4 + (l >> 4)) ^ (br & 7)) * 8];
    }
    #pragma unroll
    for (int mi = 0; mi < 4; ++mi) {
      acc[mi][0]  = MFMA16(af[mi], bfr[0], acc[mi][0]);
      acc[mi][1]  = MFMA16(af[mi], bfr[1], acc[mi][1]);
      acc[mi][PN] = MFMA16(af[mi], bfr[2], acc[mi][PN]);
    }
  }
  __builtin_amdgcn_s_setprio(0);
}

__global__ __launch_bounds__(256, 2) void k_gru3(
    const ushort* __restrict__ AX, const ushort* __restrict__ Bg3,
    const float* __restrict__ bih, const float* __restrict__ bhh,
    float* __restrict__ out) {
  __shared__ __attribute__((aligned(16))) ushort smem[2 * 16384];  // 64 KB
  ushort* sA0 = smem;               // 64*64
  ushort* sB0 = smem + 4096;        // 192*64
  ushort* sA1 = smem + 16384;
  ushort* sB1 = smem + 20480;
  int bid = blockIdx.x;
  int wk = (bid & 7) * 157 + (bid >> 3);   // XCD-bijective (1256 = 8*157)
  int panel = wk >> 2, ch = wk & 3;
  if (panel >= 313) return;
  int row0 = panel * 64;
  int bro = ch * 192;                  // Bg3 row offset
  int t = threadIdx.x, w = t >> 6, l = t & 63;

  gru3_stage(AX, Bg3, sA0, sB0, row0, bro, w, l, 0);
  __syncthreads();                     // prologue: full drain, buf0 ready

  f32x4 acc[4][4] = {};                // [mi][r, z, i_n, h_n]
  #pragma unroll
  for (int ks = 0; ks < 8; ++ks) {
    ushort* cA = (ks & 1) ? sA1 : sA0;
    ushort* cB = (ks & 1) ? sB1 : sB0;
    ushort* nA = (ks & 1) ? sA0 : sA1;
    ushort* nB = (ks & 1) ? sB0 : sB1;
    if (ks < 7) gru3_stage(AX, Bg3, nA, nB, row0, bro, w, l, ks + 1);  // 8 issues
    if (ks < 7) WAIT_BAR("8");         // prev iter's 8 retired -> cur tile ready
    else        WAIT_BAR("0");
    if (ks < 4) gru3_compute<2>(cA, cB, w, l, acc);
    else        gru3_compute<3>(cA, cB, w, l, acc);
    END_BAR();                         // all waves done reading cur buffers
  }

  int c = ch * 64 + w * 16 + (l & 15);
  float br_ = bih[c] + bhh[c];
  float bz_ = bih[256 + c] + bhh[256 + c];
  float bi_ = bih[512 + c];
  float bh_ = bhh[512 + c];
  #pragma unroll
  for (int mi = 0; mi < 4; ++mi)
    #pragma unroll
    for (int q = 0; q < 4; ++q) {
      int r = row0 + mi*16 + (l>>4)*4 + q;
      if (r < N_NODES) {
        float rg = 1.f / (1.f + __expf(-(acc[mi][0][q] + br_)));
        float zg = 1.f / (1.f + __expf(-(acc[mi][1][q] + bz_)));
        float ng = tanhf((acc[mi][2][q] + bi_) + rg * (acc[mi][3][q] + bh_));
        float xv = bf2f(AX[(size_t)r * 512 + 256 + c]);
        out[(size_t)r * 256 + c] = (1.f - zg) * ng + zg * xv;
      }
    }
}

extern "C" void kernel_launch(void* const* d_in, const int* in_sizes, int n_in,
                              void* d_out, int out_size, void* d_ws, size_t ws_size,
                              hipStream_t stream) {
  const float* h   = (const float*)d_in[0];
  const float* x   = (const float*)d_in[1];
  const float* Wfc = (const float*)d_in[3];
  const float* bfc = (const float*)d_in[4];
  const float* Wc  = (const float*)d_in[5];
  const float* Wih = (const float*)d_in[6];
  const float* Whh = (const float*)d_in[7];
  const float* bih = (const float*)d_in[8];
  const float* bhh = (const float*)d_in[9];
  const int*   eg  = (const int*)d_in[10];
  float* out = (float*)d_out;

  char* ws = (char*)d_ws;
  ushort* AX   = (ushort*)(ws);                  // MPAD*512*2 = 20,512,768
  ushort* Bg3  = (ushort*)(ws + 20512768);       //    786,432
  int*    cnt    = (int*)(ws + 21299200);        //     80,000
  int*    srcs   = (int*)(ws + 21379200);        //  5,120,000 -> 26,499,200 total

  hipMemsetAsync(cnt, 0, (size_t)N_NODES * 4, stream);

  // merged: fc (1256) | wfuse (48) | bg3hi (96) | bucket (1250)
  k_mid<<<2650, 256, 0, stream>>>(x, h, Wfc, bfc, AX, Wih, Wc, Whh, Bg3, eg, cnt, srcs);

  k_aggS<<<(N_NODES + 7) / 8, 256, 0, stream>>>(cnt, srcs, AX);

  k_gru3<<<1256, 256, 0, stream>>>(AX, Bg3, bih, bhh, out);
}